// Round 6
// baseline (82.565 us; speedup 1.0000x reference)
//
#include <hip/hip_runtime.h>

#define NPROTO 512
#define NBLK 8
#define DB 128
#define DM 1024
#define TMR 256         // query rows per block
#define PC 128          // protos per chunk

#define IDX_OFF  8388608
#define VQ_OFF   8454144
#define CL_OFF   8454145

typedef unsigned short u16;
typedef __attribute__((ext_vector_type(8))) _Float16 f16x8;
typedef __attribute__((ext_vector_type(4))) float f32x4;

// ---- ws layout (bytes) ----
#define BH_B   0u
#define BL_B   1048576u
#define CN_B   2097152u
#define PART_B 2113536u
#define WS_NEED (PART_B + 4096u)

__device__ __forceinline__ void gl_lds16(const u16* g, u16* l) {
    __builtin_amdgcn_global_load_lds(
        (const __attribute__((address_space(1))) unsigned int*)g,
        (__attribute__((address_space(3))) unsigned int*)l, 16, 0, 0);
}

// ---- prep: split codes into 2 f16 planes + per-proto sq-norms ----
__global__ __launch_bounds__(256) void vq_prep(const float* __restrict__ src,
                                               u16* __restrict__ hi,
                                               u16* __restrict__ lo,
                                               float* __restrict__ cn) {
    const int t  = threadIdx.x;
    const int p  = blockIdx.x * 32 + (t >> 3);
    const int e0 = (t & 7) * 16;
    const float* s = src + (size_t)p * DB + e0;
    float sq = 0.f;
    #pragma unroll
    for (int j = 0; j < 4; ++j) {
        float4 v = *(const float4*)(s + j * 4);
        ushort4 h, l;
        float x; _Float16 hf;
        #define S1(c, f) x = v.c; hf = (_Float16)x; h.f = __builtin_bit_cast(u16, hf); \
            hf = (_Float16)(x - (float)hf); l.f = __builtin_bit_cast(u16, hf); sq += x * x;
        S1(x, x) S1(y, y) S1(z, z) S1(w, w)
        #undef S1
        size_t o4 = ((size_t)p * DB + e0) / 4 + j;
        ((ushort4*)hi)[o4] = h;
        ((ushort4*)lo)[o4] = l;
    }
    sq += __shfl_xor(sq, 1, 64);
    sq += __shfl_xor(sq, 2, 64);
    sq += __shfl_xor(sq, 4, 64);
    if ((t & 7) == 0) cn[p] = sq;
}

// ================= fused MFMA main kernel =================
// 512 thr = 8 waves; wave w owns q-rows w*32..w*32+31 (ai=0,1), all 512 protos.
// r5 lesson: VGPR budget is set by the backend's occupancy target, which is
// derived from LDS (68KB -> 2 WG/CU -> 4 waves/EU -> 128 VGPR cap -> spill).
// Fix: waves_per_eu(1,2) + LDS>80KB forces 1 WG/CU = 2 waves/EU = 256 VGPRs.
__global__ __launch_bounds__(512)
__attribute__((amdgpu_waves_per_eu(1, 2)))
void vq_fused(
        const float* __restrict__ q, const float* __restrict__ mem,
        const u16* __restrict__ bh, const u16* __restrict__ bl,
        const float* __restrict__ cn, float* __restrict__ out,
        float* __restrict__ partials) {
    __shared__ u16 Bt[2][2][PC][64];   // [dbuf][plane][proto][d-half] = 64 KB
    __shared__ float qn_lds[TMR];
    __shared__ int   bp[TMR];
    __shared__ float red[4096];        // 16 KB (only [0..31] used) -> LDS 84 KB
                                       // > 80 KB => 1 WG/CU => 256-VGPR budget

    const int t    = threadIdx.x;
    const int lane = t & 63;
    const int w    = t >> 6;          // 0..7
    const int lrow = lane & 15;
    const int lk   = lane >> 4;       // 0..3
    const int m    = blockIdx.y;
    const int bn0  = blockIdx.x * TMR;

    // ---- staging geometry (verbatim from verified round-3/4 kernel) ----
    const u16* plbase = (w & 1) ? bl : bh;
    const int  p_l    = (w >> 1) * 32 + (lane >> 3);
    const int  sl     = lane & 7;
    const u16* g0 = plbase + ((size_t)(m * NPROTO + p_l)) * DB
                           + ((sl ^ (p_l & 7)) * 8);    // inverse-swizzled source

#define STAGE(st_, nb_) do { \
    const u16* gs_ = g0 + ((st_) >> 1) * (PC * DB) + ((st_) & 1) * 64; \
    u16* lb_ = &Bt[(nb_)][w & 1][(w >> 1) * 32][0]; \
    gl_lds16(gs_,           lb_); \
    gl_lds16(gs_ + 8 * DB,  lb_ + 8 * 64); \
    gl_lds16(gs_ + 16 * DB, lb_ + 16 * 64); \
    gl_lds16(gs_ + 24 * DB, lb_ + 24 * 64); \
} while (0)

    STAGE(0, 0);   // prefetch first B tile; overlaps A load/convert below

    // ---- A: 2 q-rows per lane, f32 -> 2 f16 planes in registers ----
    f16x8 ah[2][4], al[2][4];
    #pragma unroll
    for (int ai = 0; ai < 2; ++ai) {
        float qnp = 0.f;
        #pragma unroll
        for (int kst = 0; kst < 4; ++kst) {
            const float* src = q + (size_t)(bn0 + w * 32 + ai * 16 + lrow) * DM
                                 + m * DB + kst * 32 + lk * 8;
            float4 v0 = *(const float4*)src;
            float4 v1 = *(const float4*)(src + 4);
            f16x8 hv, lv;
            float x; _Float16 hh;
            #define SA(e, val) x = (val); hh = (_Float16)x; hv[e] = hh; \
                lv[e] = (_Float16)(x - (float)hh); qnp += x * x;
            SA(0, v0.x) SA(1, v0.y) SA(2, v0.z) SA(3, v0.w)
            SA(4, v1.x) SA(5, v1.y) SA(6, v1.z) SA(7, v1.w)
            #undef SA
            ah[ai][kst] = hv; al[ai][kst] = lv;
        }
        qnp += __shfl_xor(qnp, 16, 64);
        qnp += __shfl_xor(qnp, 32, 64);
        if (lk == 0) qn_lds[w * 32 + ai * 16 + lrow] = qnp;
    }

    float bestv[2][4]; int besti[2][4];
    #pragma unroll
    for (int ai = 0; ai < 2; ++ai)
        #pragma unroll
        for (int r = 0; r < 4; ++r) { bestv[ai][r] = 3.4e38f; besti[ai][r] = 0; }

    f32x4 acc[2][8];
    #pragma unroll
    for (int ai = 0; ai < 2; ++ai)
        #pragma unroll
        for (int fj = 0; fj < 8; ++fj) acc[ai][fj] = (f32x4){0.f, 0.f, 0.f, 0.f};

    const float* cnbase = cn + m * NPROTO + lrow;

    __syncthreads();   // buf0 staged + qn_lds visible

    float qnr[2][4];
    #pragma unroll
    for (int ai = 0; ai < 2; ++ai)
        #pragma unroll
        for (int r = 0; r < 4; ++r)
            qnr[ai][r] = qn_lds[w * 32 + ai * 16 + lk * 4 + r];

    #pragma unroll
    for (int st = 0; st < 8; ++st) {
        const int s = st & 1, buf = st & 1, ch = st >> 1;
        if (st < 7) STAGE(st + 1, buf ^ 1);
        #pragma unroll
        for (int kk = 0; kk < 2; ++kk) {
            const int kst = s * 2 + kk;
            #pragma unroll
            for (int fj = 0; fj < 8; ++fj) {
                const int rowb = fj * 16 + lrow;
                const int so   = (((kk * 4 + lk) ^ (rowb & 7)) * 8);
                f16x8 Bh = *(const f16x8*)&Bt[buf][0][rowb][so];
                f16x8 Bl = *(const f16x8*)&Bt[buf][1][rowb][so];
                #pragma unroll
                for (int ai = 0; ai < 2; ++ai) {
                    f32x4 a = acc[ai][fj];
                    a = __builtin_amdgcn_mfma_f32_16x16x32_f16(ah[ai][kst], Bh, a, 0, 0, 0);
                    a = __builtin_amdgcn_mfma_f32_16x16x32_f16(al[ai][kst], Bh, a, 0, 0, 0);
                    a = __builtin_amdgcn_mfma_f32_16x16x32_f16(ah[ai][kst], Bl, a, 0, 0, 0);
                    acc[ai][fj] = a;
                }
            }
        }
        if (s == 1) {
            // fold chunk into running argmin; dist = (qn - 2*dot) + cn (ref order)
            #pragma unroll
            for (int fj = 0; fj < 8; ++fj) {
                const int   ploc = ch * PC + fj * 16 + lrow;
                const float cnv  = cnbase[ch * PC + fj * 16];
                #pragma unroll
                for (int ai = 0; ai < 2; ++ai) {
                    #pragma unroll
                    for (int r = 0; r < 4; ++r) {
                        float d = (qnr[ai][r] - 2.0f * acc[ai][fj][r]) + cnv;
                        if (d < bestv[ai][r]) { bestv[ai][r] = d; besti[ai][r] = ploc; }
                    }
                    acc[ai][fj] = (f32x4){0.f, 0.f, 0.f, 0.f};
                }
            }
        }
        __syncthreads();
    }

    // ---- butterfly argmin over the 16 proto-lanes ----
    #pragma unroll
    for (int ai = 0; ai < 2; ++ai)
        #pragma unroll
        for (int r = 0; r < 4; ++r) {
            float v = bestv[ai][r]; int ix = besti[ai][r];
            #pragma unroll
            for (int off = 1; off < 16; off <<= 1) {
                float v2 = __shfl_xor(v, off, 64);
                int  ix2 = __shfl_xor(ix, off, 64);
                if (v2 < v || (v2 == v && ix2 < ix)) { v = v2; ix = ix2; }
            }
            bestv[ai][r] = v; besti[ai][r] = ix;
        }

    // ---- lanes lrow==0 publish results for their 8 rows ----
    if (lrow == 0) {
        float lp = 0.f;
        #pragma unroll
        for (int ai = 0; ai < 2; ++ai)
            #pragma unroll
            for (int r = 0; r < 4; ++r) {
                int row = w * 32 + ai * 16 + lk * 4 + r;
                bp[row] = besti[ai][r];
                out[(size_t)IDX_OFF + (size_t)(bn0 + row) * NBLK + m] =
                    (float)(m * NPROTO + besti[ai][r]);
                lp += bestv[ai][r];             // full distance = commitment term
            }
        red[w * 4 + lk] = lp;
    }
    __syncthreads();

    // ---- gather winning code rows (exact f32 copy) ----
    {
        int row = t >> 1, hf = t & 1;
        int bpi = bp[row];
        const float* cv = mem + ((size_t)(m * NPROTO + bpi)) * DB + hf * 64;
        float* ov = out + (size_t)(bn0 + row) * DM + m * DB + hf * 64;
        #pragma unroll
        for (int j = 0; j < 16; ++j)
            *(float4*)(ov + j * 4) = *(const float4*)(cv + j * 4);
    }
    if (t == 0) {
        float s = 0.f;
        #pragma unroll
        for (int i = 0; i < 32; ++i) s += red[i];
        partials[blockIdx.y * gridDim.x + blockIdx.x] = s;
    }
#undef STAGE
}

// ================= fallback f32 path (used only if ws too small) =============
__global__ __launch_bounds__(256) void vq_init(const float* __restrict__ mem,
                                               float* __restrict__ cn) {
    int p = blockIdx.x * 256 + threadIdx.x;
    const float* c = mem + (size_t)p * DB;
    float s = 0.f;
    #pragma unroll 8
    for (int k = 0; k < DB; k += 4) {
        float4 v = *(const float4*)(c + k);
        s += v.x * v.x + v.y * v.y + v.z * v.z + v.w * v.w;
    }
    cn[p] = s;
}

__global__ __launch_bounds__(256, 1) void vq_main_f32(const float* __restrict__ q,
                                                      const float* __restrict__ mem,
                                                      const float* __restrict__ cn,
                                                      float* __restrict__ out,
                                                      float* __restrict__ partials) {
    __shared__ float q_lds[128 * 132];
    __shared__ float c_lds[128 * 132];
    __shared__ float red[256];

    const int t    = threadIdx.x;
    const int tile = blockIdx.x;
    const int m    = blockIdx.y;
    const int tr   = t >> 4;
    const int tc   = t & 15;
    const int bn0  = tile * 128;

    const float* qbase = q + (size_t)bn0 * DM + m * DB;
    #pragma unroll
    for (int it = 0; it < 16; ++it) {
        int idx = it * 256 + t;
        int row = idx >> 5;
        int c4  = (idx & 31) << 2;
        *(float4*)&q_lds[row * 132 + c4] = *(const float4*)(qbase + (size_t)row * DM + c4);
    }

    float bestv[8]; int besti[8];
    #pragma unroll
    for (int i = 0; i < 8; ++i) { bestv[i] = 3.4e38f; besti[i] = 0; }
    const float* cbase = mem + (size_t)m * NPROTO * DB;

    for (int ch = 0; ch < 4; ++ch) {
        __syncthreads();
        const float* cb = cbase + (size_t)ch * PC * DB;
        #pragma unroll
        for (int it = 0; it < 16; ++it) {
            int idx = it * 256 + t;
            int row = idx >> 5;
            int c4  = (idx & 31) << 2;
            *(float4*)&c_lds[row * 132 + c4] = *(const float4*)(cb + row * DB + c4);
        }
        __syncthreads();

        float acc[8][8];
        #pragma unroll
        for (int i = 0; i < 8; ++i)
            #pragma unroll
            for (int j = 0; j < 8; ++j) acc[i][j] = 0.f;

        for (int d4 = 0; d4 < DB; d4 += 4) {
            float4 qa[8], cvv[8];
            #pragma unroll
            for (int i = 0; i < 8; ++i) qa[i] = *(const float4*)&q_lds[(tr + 16 * i) * 132 + d4];
            #pragma unroll
            for (int j = 0; j < 8; ++j) cvv[j] = *(const float4*)&c_lds[(tc + 16 * j) * 132 + d4];
            #pragma unroll
            for (int i = 0; i < 8; ++i)
                #pragma unroll
                for (int j = 0; j < 8; ++j) {
                    acc[i][j] += qa[i].x * cvv[j].x; acc[i][j] += qa[i].y * cvv[j].y;
                    acc[i][j] += qa[i].z * cvv[j].z; acc[i][j] += qa[i].w * cvv[j].w;
                }
        }
        #pragma unroll
        for (int i = 0; i < 8; ++i)
            #pragma unroll
            for (int j = 0; j < 8; ++j) {
                int lp = ch * PC + tc + 16 * j;
                float dist = cn[m * NPROTO + lp] - 2.0f * acc[i][j];
                if (dist < bestv[i]) { bestv[i] = dist; besti[i] = lp; }
            }
    }

    #pragma unroll
    for (int i = 0; i < 8; ++i) {
        float v = bestv[i]; int ix = besti[i];
        #pragma unroll
        for (int off = 1; off < 16; off <<= 1) {
            float v2 = __shfl_xor(v, off, 64);
            int  ix2 = __shfl_xor(ix, off, 64);
            if (v2 < v || (v2 == v && ix2 < ix)) { v = v2; ix = ix2; }
        }
        bestv[i] = v; besti[i] = ix;
    }

    float lacc = 0.f;
    #pragma unroll
    for (int i = 0; i < 8; ++i) {
        int row = tr + 16 * i;
        int bn  = bn0 + row;
        const float* cvec = cbase + (size_t)besti[i] * DB;
        float* orow = out + (size_t)bn * DM + m * DB;
        #pragma unroll
        for (int h = 0; h < 2; ++h) {
            int col = h * 64 + tc * 4;
            float4 c4v = *(const float4*)(cvec + col);
            *(float4*)(orow + col) = c4v;
            float4 qv2 = *(const float4*)&q_lds[row * 132 + col];
            float dx = c4v.x - qv2.x, dy = c4v.y - qv2.y;
            float dz = c4v.z - qv2.z, dw = c4v.w - qv2.w;
            lacc += dx * dx + dy * dy + dz * dz + dw * dw;
        }
        if (tc == 0)
            out[(size_t)IDX_OFF + (size_t)bn * NBLK + m] = (float)(m * NPROTO + besti[i]);
    }

    red[t] = lacc;
    __syncthreads();
    for (int s = 128; s > 0; s >>= 1) {
        if (t < s) red[t] += red[t + s];
        __syncthreads();
    }
    if (t == 0) partials[blockIdx.y * gridDim.x + blockIdx.x] = red[0];
}

__global__ __launch_bounds__(256) void vq_final(const float* __restrict__ partials,
                                                float* __restrict__ out, int n) {
    __shared__ float red[256];
    int t = threadIdx.x;
    float v = (t < n) ? partials[t] : 0.f;
    if (t + 256 < n) v += partials[t + 256];
    red[t] = v;
    __syncthreads();
    for (int s = 128; s > 0; s >>= 1) {
        if (t < s) red[t] += red[t + s];
        __syncthreads();
    }
    if (t == 0) {
        out[VQ_OFF] = 0.f;
        out[CL_OFF] = red[0] / 8388608.0f;
    }
}

extern "C" void kernel_launch(void* const* d_in, const int* in_sizes, int n_in,
                              void* d_out, int out_size, void* d_ws, size_t ws_size,
                              hipStream_t stream) {
    const float* q   = (const float*)d_in[0];
    const float* mem = (const float*)d_in[1];
    float* out = (float*)d_out;
    char* ws = (char*)d_ws;

    if (ws_size >= (size_t)WS_NEED) {
        u16*   bhp = (u16*)(ws + BH_B);
        u16*   blp = (u16*)(ws + BL_B);
        float* cnp = (float*)(ws + CN_B);
        float* partials = (float*)(ws + PART_B);

        vq_prep<<<128, 256, 0, stream>>>(mem, bhp, blp, cnp);
        dim3 grid(32, 8);
        vq_fused<<<grid, 512, 0, stream>>>(q, mem, bhp, blp, cnp, out, partials);
        vq_final<<<1, 256, 0, stream>>>(partials, out, 256);
    } else {
        float* cn = (float*)ws;
        float* partials = cn + 4096;
        vq_init<<<16, 256, 0, stream>>>(mem, cn);
        dim3 grid(64, 8);
        vq_main_f32<<<grid, 256, 0, stream>>>(q, mem, cn, out, partials);
        vq_final<<<1, 256, 0, stream>>>(partials, out, 512);
    }
}

// Round 7
// 61.559 us; speedup vs baseline: 1.3412x; 1.3412x over previous
//
#include <hip/hip_runtime.h>

#define NPROTO 512
#define NBLK 8
#define DB 128
#define DM 1024
#define TMR 128         // query rows per block (ai=1: 16 rows per wave)
#define PC 128          // protos per chunk

#define IDX_OFF  8388608
#define VQ_OFF   8454144
#define CL_OFF   8454145

typedef unsigned short u16;
typedef __attribute__((ext_vector_type(8))) _Float16 f16x8;
typedef __attribute__((ext_vector_type(4))) float f32x4;

// ---- ws layout (bytes) ----
#define BH_B   0u
#define BL_B   1048576u
#define CN_B   2097152u
#define PART_B 2113536u
#define WS_NEED (PART_B + 4096u)

__device__ __forceinline__ void gl_lds16(const u16* g, u16* l) {
    __builtin_amdgcn_global_load_lds(
        (const __attribute__((address_space(1))) unsigned int*)g,
        (__attribute__((address_space(3))) unsigned int*)l, 16, 0, 0);
}

// ---- prep: split codes into 2 f16 planes + per-proto sq-norms ----
__global__ __launch_bounds__(256) void vq_prep(const float* __restrict__ src,
                                               u16* __restrict__ hi,
                                               u16* __restrict__ lo,
                                               float* __restrict__ cn) {
    const int t  = threadIdx.x;
    const int p  = blockIdx.x * 32 + (t >> 3);
    const int e0 = (t & 7) * 16;
    const float* s = src + (size_t)p * DB + e0;
    float sq = 0.f;
    #pragma unroll
    for (int j = 0; j < 4; ++j) {
        float4 v = *(const float4*)(s + j * 4);
        ushort4 h, l;
        float x; _Float16 hf;
        #define S1(c, f) x = v.c; hf = (_Float16)x; h.f = __builtin_bit_cast(u16, hf); \
            hf = (_Float16)(x - (float)hf); l.f = __builtin_bit_cast(u16, hf); sq += x * x;
        S1(x, x) S1(y, y) S1(z, z) S1(w, w)
        #undef S1
        size_t o4 = ((size_t)p * DB + e0) / 4 + j;
        ((ushort4*)hi)[o4] = h;
        ((ushort4*)lo)[o4] = l;
    }
    sq += __shfl_xor(sq, 1, 64);
    sq += __shfl_xor(sq, 2, 64);
    sq += __shfl_xor(sq, 4, 64);
    if ((t & 7) == 0) cn[p] = sq;
}

// ================= fused MFMA main kernel =================
// r6 lesson: 512-thr WG is pinned to a 128-VGPR budget on this toolchain
// (4 waves/EU target; waves_per_eu + LDS>80KB both failed to raise it).
// So fit UNDER 128: ai=1 (16 rows/wave) -> live ~110 regs, zero spill.
// (512,2) empirically (r4) yields exactly the 128-reg budget.
// TMR=128, grid(64,8)=512 blocks = 2 blocks/CU -> cross-block barrier overlap.
__global__ __launch_bounds__(512, 2) void vq_fused(
        const float* __restrict__ q, const float* __restrict__ mem,
        const u16* __restrict__ bh, const u16* __restrict__ bl,
        const float* __restrict__ cn, float* __restrict__ out,
        float* __restrict__ partials) {
    __shared__ u16 Bt[2][2][PC][64];   // [dbuf][plane][proto][d-half] = 64 KB
    __shared__ float qn_lds[TMR];
    __shared__ int   bp[TMR];
    __shared__ float red[32];

    const int t    = threadIdx.x;
    const int lane = t & 63;
    const int w    = t >> 6;          // 0..7
    const int lrow = lane & 15;
    const int lk   = lane >> 4;       // 0..3
    const int m    = blockIdx.y;
    const int bn0  = blockIdx.x * TMR;

    // ---- staging geometry (verbatim from verified r3-r6 kernels) ----
    const u16* plbase = (w & 1) ? bl : bh;
    const int  p_l    = (w >> 1) * 32 + (lane >> 3);
    const int  sl     = lane & 7;
    const u16* g0 = plbase + ((size_t)(m * NPROTO + p_l)) * DB
                           + ((sl ^ (p_l & 7)) * 8);    // inverse-swizzled source

#define STAGE(st_, nb_) do { \
    const u16* gs_ = g0 + ((st_) >> 1) * (PC * DB) + ((st_) & 1) * 64; \
    u16* lb_ = &Bt[(nb_)][w & 1][(w >> 1) * 32][0]; \
    gl_lds16(gs_,           lb_); \
    gl_lds16(gs_ + 8 * DB,  lb_ + 8 * 64); \
    gl_lds16(gs_ + 16 * DB, lb_ + 16 * 64); \
    gl_lds16(gs_ + 24 * DB, lb_ + 24 * 64); \
} while (0)

    STAGE(0, 0);   // prefetch first B tile; overlaps A load/convert below

    // ---- A: 1 q-row per lane-group, f32 -> 2 f16 planes in registers ----
    f16x8 ah[4], al[4];
    float qnp = 0.f;
    #pragma unroll
    for (int kst = 0; kst < 4; ++kst) {
        const float* src = q + (size_t)(bn0 + w * 16 + lrow) * DM
                             + m * DB + kst * 32 + lk * 8;
        float4 v0 = *(const float4*)src;
        float4 v1 = *(const float4*)(src + 4);
        f16x8 hv, lv;
        float x; _Float16 hh;
        #define SA(e, val) x = (val); hh = (_Float16)x; hv[e] = hh; \
            lv[e] = (_Float16)(x - (float)hh); qnp += x * x;
        SA(0, v0.x) SA(1, v0.y) SA(2, v0.z) SA(3, v0.w)
        SA(4, v1.x) SA(5, v1.y) SA(6, v1.z) SA(7, v1.w)
        #undef SA
        ah[kst] = hv; al[kst] = lv;
    }
    qnp += __shfl_xor(qnp, 16, 64);
    qnp += __shfl_xor(qnp, 32, 64);
    if (lk == 0) qn_lds[w * 16 + lrow] = qnp;

    float bestv[4]; int besti[4];
    #pragma unroll
    for (int r = 0; r < 4; ++r) { bestv[r] = 3.4e38f; besti[r] = 0; }

    f32x4 acc[8];
    #pragma unroll
    for (int fj = 0; fj < 8; ++fj) acc[fj] = (f32x4){0.f, 0.f, 0.f, 0.f};

    const float* cnbase = cn + m * NPROTO + lrow;

    __syncthreads();   // buf0 staged + qn_lds visible

    float qnr[4];
    #pragma unroll
    for (int r = 0; r < 4; ++r) qnr[r] = qn_lds[w * 16 + lk * 4 + r];

    #pragma unroll
    for (int st = 0; st < 8; ++st) {
        const int s = st & 1, buf = st & 1, ch = st >> 1;
        if (st < 7) STAGE(st + 1, buf ^ 1);
        #pragma unroll
        for (int kk = 0; kk < 2; ++kk) {
            const int kst = s * 2 + kk;
            #pragma unroll
            for (int fj = 0; fj < 8; ++fj) {
                const int rowb = fj * 16 + lrow;
                const int so   = (((kk * 4 + lk) ^ (rowb & 7)) * 8);
                f16x8 Bh = *(const f16x8*)&Bt[buf][0][rowb][so];
                f16x8 Bl = *(const f16x8*)&Bt[buf][1][rowb][so];
                f32x4 a = acc[fj];
                a = __builtin_amdgcn_mfma_f32_16x16x32_f16(ah[kst], Bh, a, 0, 0, 0);
                a = __builtin_amdgcn_mfma_f32_16x16x32_f16(al[kst], Bh, a, 0, 0, 0);
                a = __builtin_amdgcn_mfma_f32_16x16x32_f16(ah[kst], Bl, a, 0, 0, 0);
                acc[fj] = a;
            }
        }
        if (s == 1) {
            // fold chunk into running argmin; dist = (qn - 2*dot) + cn (ref order)
            #pragma unroll
            for (int fj = 0; fj < 8; ++fj) {
                const int   ploc = ch * PC + fj * 16 + lrow;
                const float cnv  = cnbase[ch * PC + fj * 16];
                #pragma unroll
                for (int r = 0; r < 4; ++r) {
                    float d = (qnr[r] - 2.0f * acc[fj][r]) + cnv;
                    if (d < bestv[r]) { bestv[r] = d; besti[r] = ploc; }
                }
                acc[fj] = (f32x4){0.f, 0.f, 0.f, 0.f};
            }
        }
        __syncthreads();
    }

    // ---- butterfly argmin over the 16 proto-lanes ----
    #pragma unroll
    for (int r = 0; r < 4; ++r) {
        float v = bestv[r]; int ix = besti[r];
        #pragma unroll
        for (int off = 1; off < 16; off <<= 1) {
            float v2 = __shfl_xor(v, off, 64);
            int  ix2 = __shfl_xor(ix, off, 64);
            if (v2 < v || (v2 == v && ix2 < ix)) { v = v2; ix = ix2; }
        }
        bestv[r] = v; besti[r] = ix;
    }

    // ---- lanes lrow==0 publish results for their 4 rows ----
    if (lrow == 0) {
        float lp = 0.f;
        #pragma unroll
        for (int r = 0; r < 4; ++r) {
            int row = w * 16 + lk * 4 + r;
            bp[row] = besti[r];
            out[(size_t)IDX_OFF + (size_t)(bn0 + row) * NBLK + m] =
                (float)(m * NPROTO + besti[r]);
            lp += bestv[r];                     // full distance = commitment term
        }
        red[w * 4 + lk] = lp;
    }
    __syncthreads();

    // ---- gather winning code rows (exact f32 copy) ----
    {
        int row = t >> 2, qt = t & 3;
        int bpi = bp[row];
        const float* cv = mem + ((size_t)(m * NPROTO + bpi)) * DB + qt * 32;
        float* ov = out + (size_t)(bn0 + row) * DM + m * DB + qt * 32;
        #pragma unroll
        for (int j = 0; j < 8; ++j)
            *(float4*)(ov + j * 4) = *(const float4*)(cv + j * 4);
    }
    if (t == 0) {
        float s = 0.f;
        #pragma unroll
        for (int i = 0; i < 32; ++i) s += red[i];
        partials[blockIdx.y * gridDim.x + blockIdx.x] = s;
    }
#undef STAGE
}

// ================= fallback f32 path (used only if ws too small) =============
__global__ __launch_bounds__(256) void vq_init(const float* __restrict__ mem,
                                               float* __restrict__ cn) {
    int p = blockIdx.x * 256 + threadIdx.x;
    const float* c = mem + (size_t)p * DB;
    float s = 0.f;
    #pragma unroll 8
    for (int k = 0; k < DB; k += 4) {
        float4 v = *(const float4*)(c + k);
        s += v.x * v.x + v.y * v.y + v.z * v.z + v.w * v.w;
    }
    cn[p] = s;
}

__global__ __launch_bounds__(256, 1) void vq_main_f32(const float* __restrict__ q,
                                                      const float* __restrict__ mem,
                                                      const float* __restrict__ cn,
                                                      float* __restrict__ out,
                                                      float* __restrict__ partials) {
    __shared__ float q_lds[128 * 132];
    __shared__ float c_lds[128 * 132];
    __shared__ float red[256];

    const int t    = threadIdx.x;
    const int tile = blockIdx.x;
    const int m    = blockIdx.y;
    const int tr   = t >> 4;
    const int tc   = t & 15;
    const int bn0  = tile * 128;

    const float* qbase = q + (size_t)bn0 * DM + m * DB;
    #pragma unroll
    for (int it = 0; it < 16; ++it) {
        int idx = it * 256 + t;
        int row = idx >> 5;
        int c4  = (idx & 31) << 2;
        *(float4*)&q_lds[row * 132 + c4] = *(const float4*)(qbase + (size_t)row * DM + c4);
    }

    float bestv[8]; int besti[8];
    #pragma unroll
    for (int i = 0; i < 8; ++i) { bestv[i] = 3.4e38f; besti[i] = 0; }
    const float* cbase = mem + (size_t)m * NPROTO * DB;

    for (int ch = 0; ch < 4; ++ch) {
        __syncthreads();
        const float* cb = cbase + (size_t)ch * PC * DB;
        #pragma unroll
        for (int it = 0; it < 16; ++it) {
            int idx = it * 256 + t;
            int row = idx >> 5;
            int c4  = (idx & 31) << 2;
            *(float4*)&c_lds[row * 132 + c4] = *(const float4*)(cb + row * DB + c4);
        }
        __syncthreads();

        float acc[8][8];
        #pragma unroll
        for (int i = 0; i < 8; ++i)
            #pragma unroll
            for (int j = 0; j < 8; ++j) acc[i][j] = 0.f;

        for (int d4 = 0; d4 < DB; d4 += 4) {
            float4 qa[8], cvv[8];
            #pragma unroll
            for (int i = 0; i < 8; ++i) qa[i] = *(const float4*)&q_lds[(tr + 16 * i) * 132 + d4];
            #pragma unroll
            for (int j = 0; j < 8; ++j) cvv[j] = *(const float4*)&c_lds[(tc + 16 * j) * 132 + d4];
            #pragma unroll
            for (int i = 0; i < 8; ++i)
                #pragma unroll
                for (int j = 0; j < 8; ++j) {
                    acc[i][j] += qa[i].x * cvv[j].x; acc[i][j] += qa[i].y * cvv[j].y;
                    acc[i][j] += qa[i].z * cvv[j].z; acc[i][j] += qa[i].w * cvv[j].w;
                }
        }
        #pragma unroll
        for (int i = 0; i < 8; ++i)
            #pragma unroll
            for (int j = 0; j < 8; ++j) {
                int lp = ch * PC + tc + 16 * j;
                float dist = cn[m * NPROTO + lp] - 2.0f * acc[i][j];
                if (dist < bestv[i]) { bestv[i] = dist; besti[i] = lp; }
            }
    }

    #pragma unroll
    for (int i = 0; i < 8; ++i) {
        float v = bestv[i]; int ix = besti[i];
        #pragma unroll
        for (int off = 1; off < 16; off <<= 1) {
            float v2 = __shfl_xor(v, off, 64);
            int  ix2 = __shfl_xor(ix, off, 64);
            if (v2 < v || (v2 == v && ix2 < ix)) { v = v2; ix = ix2; }
        }
        bestv[i] = v; besti[i] = ix;
    }

    float lacc = 0.f;
    #pragma unroll
    for (int i = 0; i < 8; ++i) {
        int row = tr + 16 * i;
        int bn  = bn0 + row;
        const float* cvec = cbase + (size_t)besti[i] * DB;
        float* orow = out + (size_t)bn * DM + m * DB;
        #pragma unroll
        for (int h = 0; h < 2; ++h) {
            int col = h * 64 + tc * 4;
            float4 c4v = *(const float4*)(cvec + col);
            *(float4*)(orow + col) = c4v;
            float4 qv2 = *(const float4*)&q_lds[row * 132 + col];
            float dx = c4v.x - qv2.x, dy = c4v.y - qv2.y;
            float dz = c4v.z - qv2.z, dw = c4v.w - qv2.w;
            lacc += dx * dx + dy * dy + dz * dz + dw * dw;
        }
        if (tc == 0)
            out[(size_t)IDX_OFF + (size_t)bn * NBLK + m] = (float)(m * NPROTO + besti[i]);
    }

    red[t] = lacc;
    __syncthreads();
    for (int s = 128; s > 0; s >>= 1) {
        if (t < s) red[t] += red[t + s];
        __syncthreads();
    }
    if (t == 0) partials[blockIdx.y * gridDim.x + blockIdx.x] = red[0];
}

__global__ __launch_bounds__(256) void vq_final(const float* __restrict__ partials,
                                                float* __restrict__ out, int n) {
    __shared__ float red[256];
    int t = threadIdx.x;
    float v = (t < n) ? partials[t] : 0.f;
    if (t + 256 < n) v += partials[t + 256];
    red[t] = v;
    __syncthreads();
    for (int s = 128; s > 0; s >>= 1) {
        if (t < s) red[t] += red[t + s];
        __syncthreads();
    }
    if (t == 0) {
        out[VQ_OFF] = 0.f;
        out[CL_OFF] = red[0] / 8388608.0f;
    }
}

extern "C" void kernel_launch(void* const* d_in, const int* in_sizes, int n_in,
                              void* d_out, int out_size, void* d_ws, size_t ws_size,
                              hipStream_t stream) {
    const float* q   = (const float*)d_in[0];
    const float* mem = (const float*)d_in[1];
    float* out = (float*)d_out;
    char* ws = (char*)d_ws;

    if (ws_size >= (size_t)WS_NEED) {
        u16*   bhp = (u16*)(ws + BH_B);
        u16*   blp = (u16*)(ws + BL_B);
        float* cnp = (float*)(ws + CN_B);
        float* partials = (float*)(ws + PART_B);

        vq_prep<<<128, 256, 0, stream>>>(mem, bhp, blp, cnp);
        dim3 grid(64, 8);
        vq_fused<<<grid, 512, 0, stream>>>(q, mem, bhp, blp, cnp, out, partials);
        vq_final<<<1, 256, 0, stream>>>(partials, out, 512);
    } else {
        float* cn = (float*)ws;
        float* partials = cn + 4096;
        vq_init<<<16, 256, 0, stream>>>(mem, cn);
        dim3 grid(64, 8);
        vq_main_f32<<<grid, 256, 0, stream>>>(q, mem, cn, out, partials);
        vq_final<<<1, 256, 0, stream>>>(partials, out, 512);
    }
}